// Round 15
// baseline (779.124 us; speedup 1.0000x reference)
//
#include <hip/hip_runtime.h>
#include <cfloat>

#define D 768
#define V 30523
#define NR 8192               // rows = 16*512
#define BM 256
#define BN 256
#define BK 64
#define KT (D / BK)           // 12 K-tiles
#define MT (NR / BM)          // 32 row tiles
#define VT ((V + BN - 1) / BN)   // 120 col tiles
#define BUF_SZ 65536          // one K-tile: A 32K + B 32K
#define BOFF 32768            // B offset within buffer
#define UNIT 8192             // bytes per K-column unit per matrix (256 rows x 16 cols x 2B)

typedef __bf16 bf16x8 __attribute__((ext_vector_type(8)));
typedef float floatx4 __attribute__((ext_vector_type(4)));

__device__ __forceinline__ void async_ld16(const void* g, void* s) {
    __builtin_amdgcn_global_load_lds(
        (const __attribute__((address_space(1))) void*)g,
        (__attribute__((address_space(3))) void*)s, 16, 0, 0);
}

__device__ __forceinline__ unsigned short f2bf(float f) {
    unsigned u = __float_as_uint(f);
    unsigned r = (u + 0x7FFFu + ((u >> 16) & 1u)) >> 16;  // RNE
    return (unsigned short)r;
}

// ---------------- cast fp32 -> bf16 (vectorized) ----------------
__global__ void cast_bf16(const float* __restrict__ in, unsigned short* __restrict__ out, int n4) {
    int i = blockIdx.x * blockDim.x + threadIdx.x;
    int stride = gridDim.x * blockDim.x;
    for (; i < n4; i += stride) {
        float4 f = ((const float4*)in)[i];
        ushort4 o;
        o.x = f2bf(f.x); o.y = f2bf(f.y); o.z = f2bf(f.z); o.w = f2bf(f.w);
        ((ushort4*)out)[i] = o;
    }
}

// ---------------- label logits in fp32 (one wave per row) ----------------
__global__ void label_logit(const float* __restrict__ x, const float* __restrict__ W,
                            const float* __restrict__ bias, const int* __restrict__ lab,
                            float* __restrict__ out) {
    int wave = (blockIdx.x * blockDim.x + threadIdx.x) >> 6;
    int l = threadIdx.x & 63;
    if (wave >= NR) return;
    int lb = lab[wave];
    const float4* xr = (const float4*)(x + (size_t)wave * D);
    const float4* wr = (const float4*)(W + (size_t)lb * D);
    float s = 0.f;
#pragma unroll
    for (int k = 0; k < 3; ++k) {
        float4 a = xr[l + k * 64];
        float4 b4 = wr[l + k * 64];
        s += a.x * b4.x + a.y * b4.y + a.z * b4.z + a.w * b4.w;
    }
#pragma unroll
    for (int m = 1; m <= 32; m <<= 1) s += __shfl_xor(s, m);
    if (l == 0) out[wave] = s + bias[lb];
}

// ---------------- fused GEMM + per-tile logsumexp partials ----------------
// 256x256 tile, 8 waves (2M x 4N, wave tile 128x64), BK=64, double-buffered
// 128KB LDS in K-column units (stage unit p = K-cols [16p,16p+16) of A and B).
// 4 phases per K-tile: {ds_read ; wait(ledger) ; stage ; barrier ; lgkmcnt(0) ;
// setprio(1) ; 16 MFMA ; setprio(0) ; barrier}. vmcnt(2) at phases 1,3 — never
// 0 except the peeled last tile. Unit layout [256][16] bf16 is bank-optimal
// (b128 frag read = contiguous 512B per 32-lane group -> 8 acc/bank = floor).
__global__ __launch_bounds__(512, 2) void gemm_lse(
    const unsigned short* __restrict__ xb, const unsigned short* __restrict__ wb,
    const float* __restrict__ bias, float* __restrict__ pm, float* __restrict__ pl) {

    __shared__ __attribute__((aligned(16))) char smem[131072];  // 2 x (A 32K + B 32K)

    const int bid = blockIdx.x;
    const int vtile = bid / MT;          // consecutive bids share the W panel (L2)
    const int mtile = bid - vtile * MT;
    const int tid = threadIdx.x;         // 0..511
    const int l = tid & 63;
    const int w = tid >> 6;
    const int wr = w >> 2, wc = w & 3;   // 2M x 4N wave grid, wave tile 128x64
    const int lg = l >> 4, li = l & 15;  // mfma fragment coords

    // ---- staging addresses: LDS dest linear (tid*16), 1 load/thread/matrix/unit
    const int srow = tid >> 1, shalf = tid & 1;      // unit row, 16B half of 32B row
    const unsigned short* gA = xb + (size_t)(mtile * BM + srow) * D + shalf * 8;
    int brow = vtile * BN + srow;
    if (brow > V - 1) brow = V - 1;                  // clamp tail rows (masked later)
    const unsigned short* gB = wb + (size_t)brow * D + shalf * 8;
    const int ldsStage = srow * 32 + shalf * 16;     // == tid*16 within unit

    // ---- fragment read offsets: K-col k = kk*32 + lg*8  ->  unit kk*2+(lg>>1),
    //      16B half (lg&1); row*32 within unit.
    const int aoffbase = (lg >> 1) * UNIT + (lg & 1) * 16 + (wr * 128 + li) * 32;
    const int boffbase = BOFF + (lg >> 1) * UNIT + (lg & 1) * 16 + (wc * 64 + li) * 32;

    floatx4 acc[8][4];
#pragma unroll
    for (int a = 0; a < 8; ++a)
#pragma unroll
        for (int b = 0; b < 4; ++b) acc[a][b] = (floatx4){0.f, 0.f, 0.f, 0.f};

    // ---- prologue: stage K-tile 0 (units 0..3, A then B) into buf0 ----
#pragma unroll
    for (int p = 0; p < 4; ++p) {
        async_ld16(gA + p * 16, smem + p * UNIT + ldsStage);
        async_ld16(gB + p * 16, smem + BOFF + p * UNIT + ldsStage);
    }
    asm volatile("s_waitcnt vmcnt(4)" ::: "memory");  // units 0,1 landed
    __builtin_amdgcn_s_barrier();
    __builtin_amdgcn_sched_barrier(0);

    bf16x8 bfr[4];
    for (int t = 0; t < KT; ++t) {
        const char* Ab = smem + (t & 1) * BUF_SZ;
        char* Sb = (char*)smem + ((t + 1) & 1) * BUF_SZ;
        const int kg = (t + 1) * BK;
        const bool st = (t + 1 < KT);
#pragma unroll
        for (int ph = 0; ph < 4; ++ph) {
            const int kk = ph >> 1, mh = ph & 1;   // K-half, M-half of wave tile
            // ds_read this phase's fragments (data guaranteed by earlier wait+barriers)
            bf16x8 af[4];
#pragma unroll
            for (int m4 = 0; m4 < 4; ++m4)
                af[m4] = *(const bf16x8*)(Ab + kk * 16384 + aoffbase + (mh * 4 + m4) * 512);
            if (mh == 0) {
#pragma unroll
                for (int ni = 0; ni < 4; ++ni)
                    bfr[ni] = *(const bf16x8*)(Ab + kk * 16384 + boffbase + ni * 512);
            }
            // ledger waits (before this phase's stage issue):
            // ph1: retire units 2,3 of tile t (read in ph2/ph3)
            // ph3: retire units 0,1 of tile t+1 (read in ph0/ph1 of t+1)
            if (ph == 1) {
                if (st) asm volatile("s_waitcnt vmcnt(2)" ::: "memory");
                else    asm volatile("s_waitcnt vmcnt(0)" ::: "memory");  // last tile drain
            } else if (ph == 3 && st) {
                asm volatile("s_waitcnt vmcnt(2)" ::: "memory");
            }
            // stage unit ph of K-tile t+1 (buffer not being read; safe after
            // final barrier of t-1 which precedes this point)
            if (st) {
                async_ld16(gA + kg + ph * 16, Sb + ph * UNIT + ldsStage);
                async_ld16(gB + kg + ph * 16, Sb + BOFF + ph * UNIT + ldsStage);
            }
            __builtin_amdgcn_s_barrier();
            asm volatile("s_waitcnt lgkmcnt(0)" ::: "memory");
            __builtin_amdgcn_sched_barrier(0);
            __builtin_amdgcn_s_setprio(1);
#pragma unroll
            for (int m4 = 0; m4 < 4; ++m4)
#pragma unroll
                for (int ni = 0; ni < 4; ++ni)
                    acc[mh * 4 + m4][ni] = __builtin_amdgcn_mfma_f32_16x16x32_bf16(
                        af[m4], bfr[ni], acc[mh * 4 + m4][ni], 0, 0, 0);
            __builtin_amdgcn_s_setprio(0);
            __builtin_amdgcn_s_barrier();
            __builtin_amdgcn_sched_barrier(0);
        }
    }

    // ---- epilogue: bias, mask, per-row max & sumexp over this 256-col tile ----
    float bv[4];
    int valid[4];
#pragma unroll
    for (int ni = 0; ni < 4; ++ni) {
        int col = vtile * BN + wc * 64 + ni * 16 + li;
        valid[ni] = (col < V);
        bv[ni] = valid[ni] ? bias[col] : 0.f;
    }
    float* red_m = (float*)smem;           // [4][256] = 4 KB
    float* red_l = (float*)(smem + 4096);  // [4][256]
    __syncthreads();  // all waves done with K-loop LDS before reuse

#pragma unroll
    for (int mi = 0; mi < 8; ++mi) {
#pragma unroll
        for (int i = 0; i < 4; ++i) {
            float vv[4];
#pragma unroll
            for (int ni = 0; ni < 4; ++ni)
                vv[ni] = valid[ni] ? (acc[mi][ni][i] + bv[ni]) : -FLT_MAX;
            float m = fmaxf(fmaxf(vv[0], vv[1]), fmaxf(vv[2], vv[3]));
#pragma unroll
            for (int sh = 1; sh <= 8; sh <<= 1) m = fmaxf(m, __shfl_xor(m, sh));
            float s = __expf(vv[0] - m) + __expf(vv[1] - m) + __expf(vv[2] - m) + __expf(vv[3] - m);
#pragma unroll
            for (int sh = 1; sh <= 8; sh <<= 1) s += __shfl_xor(s, sh);
            if (li == 0) {
                int row = wr * 128 + mi * 16 + lg * 4 + i;  // 0..255
                red_m[wc * 256 + row] = m;
                red_l[wc * 256 + row] = s;
            }
        }
    }
    __syncthreads();
    if (tid < 256) {
        float m0 = red_m[tid],       l0 = red_l[tid];
        float m1 = red_m[256 + tid], l1 = red_l[256 + tid];
        float m2 = red_m[512 + tid], l2 = red_l[512 + tid];
        float m3 = red_m[768 + tid], l3 = red_l[768 + tid];
        float m = fmaxf(fmaxf(m0, m1), fmaxf(m2, m3));
        float ls = l0 * __expf(m0 - m) + l1 * __expf(m1 - m) +
                   l2 * __expf(m2 - m) + l3 * __expf(m3 - m);
        size_t idx = (size_t)vtile * NR + mtile * BM + tid;
        pm[idx] = m;
        pl[idx] = ls;
    }
}

// ---------------- combine partials -> mean NLL ----------------
__global__ void finalize(const float* __restrict__ pm, const float* __restrict__ pl,
                         const float* __restrict__ labl, float* __restrict__ out) {
    int r = blockIdx.x * 256 + threadIdx.x;  // 32 blocks x 256 = 8192
    float gm = -FLT_MAX, gl = 0.f;
    for (int t = 0; t < VT; ++t) {
        float m = pm[(size_t)t * NR + r];
        float s = pl[(size_t)t * NR + r];
        if (m > gm) { gl = gl * __expf(gm - m) + s; gm = m; }
        else        { gl += s * __expf(m - gm); }
    }
    float nll = logf(gl) + gm - labl[r];
#pragma unroll
    for (int m = 1; m <= 32; m <<= 1) nll += __shfl_xor(nll, m);
    __shared__ float wsum[4];
    if ((threadIdx.x & 63) == 0) wsum[threadIdx.x >> 6] = nll;
    __syncthreads();
    if (threadIdx.x == 0)
        atomicAdd(out, (wsum[0] + wsum[1] + wsum[2] + wsum[3]) * (1.0f / NR));
}

extern "C" void kernel_launch(void* const* d_in, const int* in_sizes, int n_in,
                              void* d_out, int out_size, void* d_ws, size_t ws_size,
                              hipStream_t stream) {
    const float* x = (const float*)d_in[0];
    const float* W = (const float*)d_in[1];
    const float* b = (const float*)d_in[2];
    const int* lab = (const int*)d_in[3];
    float* out = (float*)d_out;

    char* ws = (char*)d_ws;
    unsigned short* xb = (unsigned short*)ws;                      // 8192*768*2   = 12,582,912 B
    unsigned short* wb = (unsigned short*)(ws + 12582912);         // 30523*768*2  = 46,883,328 B
    float* pm = (float*)(ws + 12582912 + 46883328);                // VT*NR*4      =  3,932,160 B
    float* pl = pm + (size_t)VT * NR;                              //              =  3,932,160 B
    float* labl = pl + (size_t)VT * NR;                            // 8192*4

    hipMemsetAsync(d_out, 0, sizeof(float), stream);
    cast_bf16<<<1024, 256, 0, stream>>>(x, xb, (NR * D) / 4);
    cast_bf16<<<2048, 256, 0, stream>>>(W, wb, (V * D) / 4);
    label_logit<<<NR / 4, 256, 0, stream>>>(x, W, b, lab, labl);
    gemm_lse<<<MT * VT, 512, 0, stream>>>(xb, wb, b, pm, pl);
    finalize<<<NR / 256, 256, 0, stream>>>(pm, pl, labl, out);
}